// Round 1
// baseline (2631.537 us; speedup 1.0000x reference)
//
#include <hip/hip_runtime.h>

typedef long long ll;
constexpr int HID = 256;

// ---------------- diagnostics ----------------
__global__ void k_diag(float* out, int n, float val){
  int i = blockIdx.x*256 + threadIdx.x;
  if (i < n) out[i] = val;
}

// flag=1 if edge_index is int64 (all high words of first 2048 entries zero)
__global__ void k_detect(const int* ei, int* flag){
  __shared__ int bad;
  if (threadIdx.x == 0) bad = 0;
  __syncthreads();
  for (int i = threadIdx.x; i < 2048; i += 256)
    if (ei[2*i+1] != 0) bad = 1;   // benign race: only writes 1
  __syncthreads();
  if (threadIdx.x == 0) *flag = bad ? 0 : 1;
}

// ---------------- graph preprocessing ----------------
__global__ void k_count(const int* ei, ll E, const int* flag, int* cnt){
  ll i = (ll)blockIdx.x*256 + threadIdx.x;
  if (i >= E) return;
  int f = *flag;
  int d = f ? (int)((const ll*)ei)[E + i] : ei[E + i];
  atomicAdd(&cnt[d], 1);
}

__global__ void k_scan1024(const int* cnt, int* row_ptr, int n){
  __shared__ int s[1024];
  int t = threadIdx.x;
  int chunk = (n + 1023) >> 10;
  int lo = t*chunk, hi = min(lo + chunk, n);
  int sum = 0;
  for (int i = lo; i < hi; ++i) sum += cnt[i];
  s[t] = sum; __syncthreads();
  for (int off = 1; off < 1024; off <<= 1){
    int add = (t >= off) ? s[t - off] : 0;
    __syncthreads();
    s[t] += add;
    __syncthreads();
  }
  int run = (t == 0) ? 0 : s[t-1];
  for (int i = lo; i < hi; ++i){ row_ptr[i] = run; run += cnt[i]; }
  if (t == 0) row_ptr[n] = s[1023];
}

__global__ void k_dinv(const int* cnt, const float* x, float* dinv, float* xd, int n){
  int i = blockIdx.x*256 + threadIdx.x;
  if (i >= n) return;
  float dv = 1.0f / sqrtf((float)(cnt[i] + 1));  // +1 self-loop
  dinv[i] = dv;
  xd[i] = x[i] * dv;
}

__global__ void k_place(const int* ei, ll E, const int* flag, int* fill, int* col){
  ll i = (ll)blockIdx.x*256 + threadIdx.x;
  if (i >= E) return;
  int f = *flag;
  int s, d;
  if (f){ const ll* e64 = (const ll*)ei; s = (int)e64[i]; d = (int)e64[E + i]; }
  else  { s = ei[i]; d = ei[E + i]; }
  int p = atomicAdd(&fill[d], 1);
  col[p] = s;
}

// layer 1 is rank-1: g[d] = xd[d] + sum_{s->d} xd[s]
__global__ void k_layer1(const float* __restrict__ xd, const int* __restrict__ row_ptr,
                         const int* __restrict__ col, float* __restrict__ g, int n){
  int i = blockIdx.x*256 + threadIdx.x;
  if (i >= n) return;
  float s = xd[i];
  int e0 = row_ptr[i], e1 = row_ptr[i+1];
  for (int e = e0; e < e1; ++e) s += xd[col[e]];
  g[i] = s;
}

// ---------------- per-layer GEMM: ts = relu-transform(Ain) @ W * dinv_row ----------------
// MODE 0: A[v][k] = relu(dinv[v]*g[v]*W1[k] + b1[k])   (reads scalar g)
// MODE 1: A[v][k] = relu(dinv[v]*acc[v][k] + b[k])     (reads acc [N,H])
template<int MODE>
__global__ __launch_bounds__(256) void k_gemm(
  const float* __restrict__ Ain, const float* __restrict__ Wt,
  const float* __restrict__ bias, const float* __restrict__ W1,
  const float* __restrict__ dinv, float* __restrict__ ts, int n)
{
  __shared__ float As[32][HID];     // 32 KB
  int t = threadIdx.x;              // output column
  int r0 = blockIdx.x * 32;

  // stage A tile with fused activation: 32x256 floats = 2048 float4s, 8 per thread
  for (int i = 0; i < 8; ++i){
    int f4  = t + i*256;
    int row = f4 >> 6;
    int c4  = f4 & 63;
    int v   = r0 + row;
    float4 a = make_float4(0.f, 0.f, 0.f, 0.f);
    if (v < n){
      float dv = dinv[v];
      float4 bb = ((const float4*)bias)[c4];
      if (MODE == 0){
        float gv = dv * Ain[v];
        float4 w1 = ((const float4*)W1)[c4];
        a.x = fmaxf(fmaf(gv, w1.x, bb.x), 0.f);
        a.y = fmaxf(fmaf(gv, w1.y, bb.y), 0.f);
        a.z = fmaxf(fmaf(gv, w1.z, bb.z), 0.f);
        a.w = fmaxf(fmaf(gv, w1.w, bb.w), 0.f);
      } else {
        float4 av = ((const float4*)(Ain + (size_t)v*HID))[c4];
        a.x = fmaxf(fmaf(dv, av.x, bb.x), 0.f);
        a.y = fmaxf(fmaf(dv, av.y, bb.y), 0.f);
        a.z = fmaxf(fmaf(dv, av.z, bb.z), 0.f);
        a.w = fmaxf(fmaf(dv, av.w, bb.w), 0.f);
      }
    }
    ((float4*)As[row])[c4] = a;
  }
  __syncthreads();

  float acc[32];
  #pragma unroll
  for (int r = 0; r < 32; ++r) acc[r] = 0.f;

  #pragma unroll 4
  for (int k0 = 0; k0 < HID; k0 += 4){
    float w0 = Wt[(k0+0)*HID + t];
    float w1 = Wt[(k0+1)*HID + t];
    float w2 = Wt[(k0+2)*HID + t];
    float w3 = Wt[(k0+3)*HID + t];
    #pragma unroll
    for (int r = 0; r < 32; ++r){
      float4 a = *(const float4*)&As[r][k0];   // uniform addr -> LDS broadcast
      acc[r] = fmaf(a.x, w0, fmaf(a.y, w1, fmaf(a.z, w2, fmaf(a.w, w3, acc[r]))));
    }
  }

  int rmax = min(32, n - r0);
  for (int r = 0; r < rmax; ++r){
    int v = r0 + r;
    ts[(size_t)v*HID + t] = dinv[v] * acc[r];  // pre-scale by dinv[src]
  }
}

// ---------------- propagate: acc[d] = ts[d] + sum_{e in CSR[d]} ts[col[e]] ----------------
__global__ __launch_bounds__(256) void k_scatter(
  const float* __restrict__ ts, const int* __restrict__ row_ptr,
  const int* __restrict__ col, float* __restrict__ acc, int n)
{
  int w = (int)((blockIdx.x*256 + threadIdx.x) >> 6);  // node = global wave id
  int lane = threadIdx.x & 63;
  if (w >= n) return;
  const float4* tsp = (const float4*)ts;
  float4 a = tsp[(size_t)w*64 + lane];                 // self-loop term
  int e0 = row_ptr[w], e1 = row_ptr[w+1];
  int e = e0;
  for (; e + 2 <= e1; e += 2){
    int c0 = col[e], c1 = col[e+1];
    float4 v0 = tsp[(size_t)c0*64 + lane];
    float4 v1 = tsp[(size_t)c1*64 + lane];
    a.x += v0.x; a.y += v0.y; a.z += v0.z; a.w += v0.w;
    a.x += v1.x; a.y += v1.y; a.z += v1.z; a.w += v1.w;
  }
  if (e < e1){
    int c = col[e];
    float4 v = tsp[(size_t)c*64 + lane];
    a.x += v.x; a.y += v.y; a.z += v.z; a.w += v.w;
  }
  ((float4*)acc)[(size_t)w*64 + lane] = a;
}

// ---------------- final: out[v] = relu(dinv*acc + b) . Wc + bc ----------------
__global__ __launch_bounds__(256) void k_out(
  const float* __restrict__ acc, const float* __restrict__ bias,
  const float* __restrict__ Wc, const float* __restrict__ bc,
  const float* __restrict__ dinv, float* __restrict__ out, int n)
{
  int w = (int)((blockIdx.x*256 + threadIdx.x) >> 6);
  int lane = threadIdx.x & 63;
  if (w >= n) return;
  float dv = dinv[w];
  float4 a  = ((const float4*)acc)[(size_t)w*64 + lane];
  float4 bb = ((const float4*)bias)[lane];
  float4 wc = ((const float4*)Wc)[lane];
  float s = fmaxf(fmaf(dv, a.x, bb.x), 0.f)*wc.x
          + fmaxf(fmaf(dv, a.y, bb.y), 0.f)*wc.y
          + fmaxf(fmaf(dv, a.z, bb.z), 0.f)*wc.z
          + fmaxf(fmaf(dv, a.w, bb.w), 0.f)*wc.w;
  #pragma unroll
  for (int off = 32; off; off >>= 1) s += __shfl_down(s, off, 64);
  if (lane == 0) out[w] = s + bc[0];
}

// ---------------- launch ----------------
extern "C" void kernel_launch(void* const* d_in, const int* in_sizes, int n_in,
                              void* d_out, int out_size, void* d_ws, size_t ws_size,
                              hipStream_t stream)
{
  const float* x  = (const float*)d_in[0];
  const int*   ei = (const int*)d_in[1];
  const float* W1 = (const float*)d_in[2];
  const float* b1 = (const float*)d_in[3];
  const float* Wm = (const float*)d_in[4];
  const float* bm = (const float*)d_in[5];
  const float* Wc = (const float*)d_in[6];
  const float* bc = (const float*)d_in[7];
  float* out = (float*)d_out;
  const int N = in_sizes[0];
  const ll  E = in_sizes[1] / 2;

  char* ws = (char*)d_ws;
  size_t off = 0;
  auto carve = [&](size_t bytes)->char*{
    char* p = ws + off; off += (bytes + 255) & ~(size_t)255; return p;
  };
  int*   cnt     = (int*)  carve((size_t)N*4);
  int*   row_ptr = (int*)  carve((size_t)(N+1)*4);
  int*   fill    = (int*)  carve((size_t)N*4);
  float* dinv    = (float*)carve((size_t)N*4);
  float* xd      = (float*)carve((size_t)N*4);
  float* g       = (float*)carve((size_t)N*4);
  int*   flag    = (int*)  carve(256);
  int*   col     = (int*)  carve((size_t)E*4);
  float* ts      = (float*)carve((size_t)N*HID*4);
  float* acc     = (float*)carve((size_t)N*HID*4);
  if (off > ws_size){
    // diagnostic: workspace too small — emit its size in MB so it's visible in absmax
    k_diag<<<(out_size+255)/256, 256, 0, stream>>>(out, out_size, (float)(ws_size >> 20));
    return;
  }

  hipMemsetAsync(cnt, 0, (size_t)N*4, stream);
  k_detect<<<1, 256, 0, stream>>>(ei, flag);
  int eblocks = (int)((E + 255) / 256);
  k_count<<<eblocks, 256, 0, stream>>>(ei, E, flag, cnt);
  k_scan1024<<<1, 1024, 0, stream>>>(cnt, row_ptr, N);
  k_dinv<<<(N+255)/256, 256, 0, stream>>>(cnt, x, dinv, xd, N);
  hipMemcpyAsync(fill, row_ptr, (size_t)N*4, hipMemcpyDeviceToDevice, stream);
  k_place<<<eblocks, 256, 0, stream>>>(ei, E, flag, fill, col);
  k_layer1<<<(N+255)/256, 256, 0, stream>>>(xd, row_ptr, col, g, N);

  int gblocks = (N + 31) / 32;
  int sblocks = (N + 3) / 4;
  // layer 2: reads rank-1 h1 implicitly from g/W1/b1
  k_gemm<0><<<gblocks, 256, 0, stream>>>(g, Wm, b1, W1, dinv, ts, N);
  k_scatter<<<sblocks, 256, 0, stream>>>(ts, row_ptr, col, acc, N);
  // layers 3..10
  for (int l = 0; l < 8; ++l){
    k_gemm<1><<<gblocks, 256, 0, stream>>>(acc, Wm, bm, nullptr, dinv, ts, N);
    k_scatter<<<sblocks, 256, 0, stream>>>(ts, row_ptr, col, acc, N);
  }
  k_out<<<sblocks, 256, 0, stream>>>(acc, bm, Wc, bc, dinv, out, N);
}

// Round 2
// 1574.727 us; speedup vs baseline: 1.6711x; 1.6711x over previous
//
#include <hip/hip_runtime.h>

typedef long long ll;
typedef __attribute__((ext_vector_type(8))) short short8;
typedef __attribute__((ext_vector_type(4))) float f32x4;
constexpr int HID = 256;
constexpr int LDSS = 264;   // LDS row stride in shorts: 528B, 16B-aligned, breaks pow2 banks

__device__ inline ushort f2bf(float f){
  uint u = __float_as_uint(f);
  u += 0x7FFFu + ((u >> 16) & 1u);
  return (ushort)(u >> 16);
}

// ---------------- diagnostics ----------------
__global__ void k_diag(float* out, int n, float val){
  int i = blockIdx.x*256 + threadIdx.x;
  if (i < n) out[i] = val;
}

// flag=1 if edge_index is int64 (all high words of first 2048 entries zero)
__global__ void k_detect(const int* ei, int* flag){
  __shared__ int bad;
  if (threadIdx.x == 0) bad = 0;
  __syncthreads();
  for (int i = threadIdx.x; i < 2048; i += 256)
    if (ei[2*i+1] != 0) bad = 1;
  __syncthreads();
  if (threadIdx.x == 0) *flag = bad ? 0 : 1;
}

// ---------------- graph preprocessing ----------------
__global__ void k_count(const int* ei, ll E, const int* flag, int* cnt){
  ll i = (ll)blockIdx.x*256 + threadIdx.x;
  if (i >= E) return;
  int f = *flag;
  int d = f ? (int)((const ll*)ei)[E + i] : ei[E + i];
  atomicAdd(&cnt[d], 1);
}

__global__ void k_scan1024(const int* cnt, int* row_ptr, int n){
  __shared__ int s[1024];
  int t = threadIdx.x;
  int chunk = (n + 1023) >> 10;
  int lo = t*chunk, hi = min(lo + chunk, n);
  int sum = 0;
  for (int i = lo; i < hi; ++i) sum += cnt[i];
  s[t] = sum; __syncthreads();
  for (int off = 1; off < 1024; off <<= 1){
    int add = (t >= off) ? s[t - off] : 0;
    __syncthreads();
    s[t] += add;
    __syncthreads();
  }
  int run = (t == 0) ? 0 : s[t-1];
  for (int i = lo; i < hi; ++i){ row_ptr[i] = run; run += cnt[i]; }
  if (t == 0) row_ptr[n] = s[1023];
}

__global__ void k_dinv(const int* cnt, const float* x, float* dinv, float* xd, int n){
  int i = blockIdx.x*256 + threadIdx.x;
  if (i >= n) return;
  float dv = 1.0f / sqrtf((float)(cnt[i] + 1));
  dinv[i] = dv;
  xd[i] = x[i] * dv;
}

__global__ void k_place(const int* ei, ll E, const int* flag, int* fill, int* col){
  ll i = (ll)blockIdx.x*256 + threadIdx.x;
  if (i >= E) return;
  int f = *flag;
  int s, d;
  if (f){ const ll* e64 = (const ll*)ei; s = (int)e64[i]; d = (int)e64[E + i]; }
  else  { s = ei[i]; d = ei[E + i]; }
  int p = atomicAdd(&fill[d], 1);
  col[p] = s;
}

// layer 1 is rank-1: g[d] = xd[d] + sum_{s->d} xd[s]
__global__ void k_layer1(const float* __restrict__ xd, const int* __restrict__ row_ptr,
                         const int* __restrict__ col, float* __restrict__ g, int n){
  int i = blockIdx.x*256 + threadIdx.x;
  if (i >= n) return;
  float s = xd[i];
  int e0 = row_ptr[i], e1 = row_ptr[i+1];
  for (int e = e0; e < e1; ++e) s += xd[col[e]];
  g[i] = s;
}

// ---------------- W split: fp32 -> (hi,lo) bf16, MFMA-fragment-major ----------------
// Bt layout: part(0=hi,1=lo) * 8192 + ((nb*8 + kc)*64 + lane), each entry short8:
//   element j = W[kc*32 + (lane>>4)*8 + j][nb*16 + (lane&15)]
__global__ void k_splitW(const float* __restrict__ W, short* __restrict__ Bt){
  int idx = blockIdx.x*256 + threadIdx.x;
  if (idx >= 16*8*64) return;
  int nb = idx >> 9, kc = (idx >> 6) & 7, l = idx & 63;
  short8 hi, lo;
  #pragma unroll
  for (int j = 0; j < 8; ++j){
    int k = kc*32 + ((l >> 4) * 8) + j;
    int c = nb*16 + (l & 15);
    float wv = W[k*HID + c];
    ushort h = f2bf(wv);
    float hf = __uint_as_float((uint)h << 16);
    hi[j] = (short)h;
    lo[j] = (short)f2bf(wv - hf);
  }
  ((short8*)Bt)[idx] = hi;
  ((short8*)Bt)[8192 + idx] = lo;
}

// ---------------- MFMA GEMM: ts = relu-transform(Ain) @ W * dinv_row ----------------
// MODE 0: A[v][k] = relu(dinv[v]*g[v]*W1[k] + b1[k])
// MODE 1: A[v][k] = relu(dinv[v]*acc[v][k] + b[k])
// bf16-split: C = Ah*Bh + Al*Bh + Ah*Bl (fp32 accumulate)
template<int MODE>
__global__ __launch_bounds__(256, 2) void k_gemm_mfma(
  const float* __restrict__ Ain, const short* __restrict__ Bt,
  const float* __restrict__ bias, const float* __restrict__ W1,
  const float* __restrict__ dinv, float* __restrict__ ts, int n)
{
  __shared__ short Ah[64*LDSS];
  __shared__ short Al[64*LDSS];
  int t = threadIdx.x;
  int r0 = blockIdx.x * 64;

  // ---- stage A tile (64 rows x 256 cols), fused transform + hi/lo split ----
  #pragma unroll
  for (int i = 0; i < 8; ++i){
    int id  = i*256 + t;           // 0..2047 : 16B-chunk id
    int row = id >> 5;             // 0..63
    int c16 = id & 31;             // 8-col chunk within row
    int v   = r0 + row;
    short8 hi8 = {0,0,0,0,0,0,0,0}, lo8 = {0,0,0,0,0,0,0,0};
    if (v < n){
      float dv = dinv[v];
      float vals[8];
      if (MODE == 0){
        float gv = dv * Ain[v];
        const float4* wp = (const float4*)(W1 + c16*8);
        const float4* bp = (const float4*)(bias + c16*8);
        float4 w0 = wp[0], w1 = wp[1], b0 = bp[0], b1 = bp[1];
        vals[0]=fmaf(gv,w0.x,b0.x); vals[1]=fmaf(gv,w0.y,b0.y);
        vals[2]=fmaf(gv,w0.z,b0.z); vals[3]=fmaf(gv,w0.w,b0.w);
        vals[4]=fmaf(gv,w1.x,b1.x); vals[5]=fmaf(gv,w1.y,b1.y);
        vals[6]=fmaf(gv,w1.z,b1.z); vals[7]=fmaf(gv,w1.w,b1.w);
      } else {
        const float4* ap = (const float4*)(Ain + (size_t)v*HID + c16*8);
        const float4* bp = (const float4*)(bias + c16*8);
        float4 a0 = ap[0], a1 = ap[1], b0 = bp[0], b1 = bp[1];
        vals[0]=fmaf(dv,a0.x,b0.x); vals[1]=fmaf(dv,a0.y,b0.y);
        vals[2]=fmaf(dv,a0.z,b0.z); vals[3]=fmaf(dv,a0.w,b0.w);
        vals[4]=fmaf(dv,a1.x,b1.x); vals[5]=fmaf(dv,a1.y,b1.y);
        vals[6]=fmaf(dv,a1.z,b1.z); vals[7]=fmaf(dv,a1.w,b1.w);
      }
      #pragma unroll
      for (int j = 0; j < 8; ++j){
        float a = fmaxf(vals[j], 0.f);
        ushort h = f2bf(a);
        float hf = __uint_as_float((uint)h << 16);
        hi8[j] = (short)h;
        lo8[j] = (short)f2bf(a - hf);
      }
    }
    int off = row*LDSS + c16*8;
    *(short8*)&Ah[off] = hi8;
    *(short8*)&Al[off] = lo8;
  }
  __syncthreads();

  // ---- MFMA: wave w covers cols [w*64, w*64+64) ----
  int l = t & 63, w = t >> 6;
  const short8* Btv = (const short8*)Bt;
  f32x4 acc[4][4];
  #pragma unroll
  for (int m = 0; m < 4; ++m)
    #pragma unroll
    for (int nf = 0; nf < 4; ++nf)
      acc[m][nf] = (f32x4){0.f,0.f,0.f,0.f};

  for (int kc = 0; kc < 8; ++kc){
    short8 ah[4], al[4];
    #pragma unroll
    for (int m = 0; m < 4; ++m){
      int row = m*16 + (l & 15);
      int off = row*LDSS + (kc*4 + (l >> 4))*8;
      ah[m] = *(const short8*)&Ah[off];
      al[m] = *(const short8*)&Al[off];
    }
    #pragma unroll
    for (int nf = 0; nf < 4; ++nf){
      int nb = w*4 + nf;
      short8 bh = Btv[(size_t)(nb*8 + kc)*64 + l];
      short8 bl = Btv[(size_t)8192 + (nb*8 + kc)*64 + l];
      #pragma unroll
      for (int m = 0; m < 4; ++m){
        acc[m][nf] = __builtin_amdgcn_mfma_f32_16x16x32_bf16(ah[m], bh, acc[m][nf], 0,0,0);
        acc[m][nf] = __builtin_amdgcn_mfma_f32_16x16x32_bf16(al[m], bh, acc[m][nf], 0,0,0);
        acc[m][nf] = __builtin_amdgcn_mfma_f32_16x16x32_bf16(ah[m], bl, acc[m][nf], 0,0,0);
      }
    }
  }

  // ---- store, pre-scaled by dinv[src] ----
  #pragma unroll
  for (int m = 0; m < 4; ++m){
    int rowb = r0 + m*16 + ((l >> 4)*4);
    #pragma unroll
    for (int r = 0; r < 4; ++r){
      int v = rowb + r;
      if (v < n){
        float dv = dinv[v];
        #pragma unroll
        for (int nf = 0; nf < 4; ++nf){
          int colb = w*64 + nf*16 + (l & 15);
          ts[(size_t)v*HID + colb] = dv * acc[m][nf][r];
        }
      }
    }
  }
}

// ---------------- propagate: acc[d] = ts[d] + sum_{e in CSR[d]} ts[col[e]] ----------------
__global__ __launch_bounds__(256) void k_scatter(
  const float* __restrict__ ts, const int* __restrict__ row_ptr,
  const int* __restrict__ col, float* __restrict__ acc, int n)
{
  int w = (int)((blockIdx.x*256 + threadIdx.x) >> 6);
  int lane = threadIdx.x & 63;
  if (w >= n) return;
  const float4* tsp = (const float4*)ts;
  float4 a = tsp[(size_t)w*64 + lane];
  int e0 = row_ptr[w], e1 = row_ptr[w+1];
  int e = e0;
  for (; e + 2 <= e1; e += 2){
    int c0 = col[e], c1 = col[e+1];
    float4 v0 = tsp[(size_t)c0*64 + lane];
    float4 v1 = tsp[(size_t)c1*64 + lane];
    a.x += v0.x; a.y += v0.y; a.z += v0.z; a.w += v0.w;
    a.x += v1.x; a.y += v1.y; a.z += v1.z; a.w += v1.w;
  }
  if (e < e1){
    int c = col[e];
    float4 v = tsp[(size_t)c*64 + lane];
    a.x += v.x; a.y += v.y; a.z += v.z; a.w += v.w;
  }
  ((float4*)acc)[(size_t)w*64 + lane] = a;
}

// ---------------- final: out[v] = relu(dinv*acc + b) . Wc + bc ----------------
__global__ __launch_bounds__(256) void k_out(
  const float* __restrict__ acc, const float* __restrict__ bias,
  const float* __restrict__ Wc, const float* __restrict__ bc,
  const float* __restrict__ dinv, float* __restrict__ out, int n)
{
  int w = (int)((blockIdx.x*256 + threadIdx.x) >> 6);
  int lane = threadIdx.x & 63;
  if (w >= n) return;
  float dv = dinv[w];
  float4 a  = ((const float4*)acc)[(size_t)w*64 + lane];
  float4 bb = ((const float4*)bias)[lane];
  float4 wc = ((const float4*)Wc)[lane];
  float s = fmaxf(fmaf(dv, a.x, bb.x), 0.f)*wc.x
          + fmaxf(fmaf(dv, a.y, bb.y), 0.f)*wc.y
          + fmaxf(fmaf(dv, a.z, bb.z), 0.f)*wc.z
          + fmaxf(fmaf(dv, a.w, bb.w), 0.f)*wc.w;
  #pragma unroll
  for (int off = 32; off; off >>= 1) s += __shfl_down(s, off, 64);
  if (lane == 0) out[w] = s + bc[0];
}

// ---------------- launch ----------------
extern "C" void kernel_launch(void* const* d_in, const int* in_sizes, int n_in,
                              void* d_out, int out_size, void* d_ws, size_t ws_size,
                              hipStream_t stream)
{
  const float* x  = (const float*)d_in[0];
  const int*   ei = (const int*)d_in[1];
  const float* W1 = (const float*)d_in[2];
  const float* b1 = (const float*)d_in[3];
  const float* Wm = (const float*)d_in[4];
  const float* bm = (const float*)d_in[5];
  const float* Wc = (const float*)d_in[6];
  const float* bc = (const float*)d_in[7];
  float* out = (float*)d_out;
  const int N = in_sizes[0];
  const ll  E = in_sizes[1] / 2;

  char* ws = (char*)d_ws;
  size_t off = 0;
  auto carve = [&](size_t bytes)->char*{
    char* p = ws + off; off += (bytes + 255) & ~(size_t)255; return p;
  };
  int*   cnt     = (int*)  carve((size_t)N*4);
  int*   row_ptr = (int*)  carve((size_t)(N+1)*4);
  int*   fill    = (int*)  carve((size_t)N*4);
  float* dinv    = (float*)carve((size_t)N*4);
  float* xd      = (float*)carve((size_t)N*4);
  float* g       = (float*)carve((size_t)N*4);
  int*   flag    = (int*)  carve(256);
  short* Bt      = (short*)carve((size_t)2*8192*8*2);   // 256 KB
  int*   col     = (int*)  carve((size_t)E*4);
  float* ts      = (float*)carve((size_t)N*HID*4);
  float* acc     = (float*)carve((size_t)N*HID*4);
  if (off > ws_size){
    k_diag<<<(out_size+255)/256, 256, 0, stream>>>(out, out_size, (float)(ws_size >> 20));
    return;
  }

  hipMemsetAsync(cnt, 0, (size_t)N*4, stream);
  k_detect<<<1, 256, 0, stream>>>(ei, flag);
  int eblocks = (int)((E + 255) / 256);
  k_count<<<eblocks, 256, 0, stream>>>(ei, E, flag, cnt);
  k_scan1024<<<1, 1024, 0, stream>>>(cnt, row_ptr, N);
  k_dinv<<<(N+255)/256, 256, 0, stream>>>(cnt, x, dinv, xd, N);
  hipMemcpyAsync(fill, row_ptr, (size_t)N*4, hipMemcpyDeviceToDevice, stream);
  k_place<<<eblocks, 256, 0, stream>>>(ei, E, flag, fill, col);
  k_splitW<<<32, 256, 0, stream>>>(Wm, Bt);
  k_layer1<<<(N+255)/256, 256, 0, stream>>>(xd, row_ptr, col, g, N);

  int gblocks = (N + 63) / 64;
  int sblocks = (N + 3) / 4;
  k_gemm_mfma<0><<<gblocks, 256, 0, stream>>>(g, Bt, b1, W1, dinv, ts, N);
  k_scatter<<<sblocks, 256, 0, stream>>>(ts, row_ptr, col, acc, N);
  for (int l = 0; l < 8; ++l){
    k_gemm_mfma<1><<<gblocks, 256, 0, stream>>>(acc, Bt, bm, nullptr, dinv, ts, N);
    k_scatter<<<sblocks, 256, 0, stream>>>(ts, row_ptr, col, acc, N);
  }
  k_out<<<sblocks, 256, 0, stream>>>(acc, bm, Wc, bc, dinv, out, N);
}